// Round 1
// baseline (1004.836 us; speedup 1.0000x reference)
//
#include <hip/hip_runtime.h>
#include <math.h>

#define BB  4
#define SS  2048
#define DMM 128
#define HH  8
#define DKK 16

// workspace float offsets
#define O_QP 0          // [B*H][S][32]  q' = [0.25*q || pos_q]
#define O_KP 2097152    // [B*H][S][32]  k' = [k || pos_k]
#define O_VP 4194304    // [B*H][S][16]
#define O_X  5242880    // [B][S][128]   attention output (pre out-proj)
#define O_WT 6291456    // 4 x 128x128 transposed weights (W0,W1,W2,Wo)

__global__ __launch_bounds__(256) void k_transpose(
    const float* __restrict__ W0, const float* __restrict__ W1,
    const float* __restrict__ W2, const float* __restrict__ Wo,
    float* __restrict__ WT)
{
    int i = blockIdx.x * 256 + threadIdx.x;      // 0..16383
    const float* src = (blockIdx.y == 0) ? W0 : (blockIdx.y == 1) ? W1
                     : (blockIdx.y == 2) ? W2 : Wo;
    float* dst = WT + blockIdx.y * (DMM * DMM);
    // W[c][d] -> WT[d][c]
    dst[(i & 127) * 128 + (i >> 7)] = src[i];
}

// 5 projections fused: p=0 q(W0), 1 k(W1), 2 v(W2), 3 pos_q(W0), 4 pos_k(W1)
#define R1 16
__global__ __launch_bounds__(640) void k_proj(
    const float* __restrict__ q_in, const float* __restrict__ k_in,
    const float* __restrict__ v_in, const float* __restrict__ p_in,
    const float* __restrict__ WT,
    const float* __restrict__ b0, const float* __restrict__ b1,
    const float* __restrict__ b2,
    float* __restrict__ qp, float* __restrict__ kp, float* __restrict__ vp)
{
    __shared__ float xs[4][R1][DMM];   // 32 KB
    int tid = threadIdx.x;
    int row0 = blockIdx.x * R1;
    for (int idx = tid; idx < 4 * R1 * 32; idx += 640) {
        int t = idx >> 9, rem = idx & 511;
        int r = rem >> 5, c4 = rem & 31;
        const float* sp = (t == 0) ? q_in : (t == 1) ? k_in : (t == 2) ? v_in : p_in;
        float4 val = ((const float4*)(sp + (size_t)(row0 + r) * DMM))[c4];
        ((float4*)&xs[t][r][0])[c4] = val;
    }
    __syncthreads();

    int p = tid >> 7, c = tid & 127;               // wave-uniform p
    int tsel = (p < 3) ? p : 3;                    // p3,p4 read pos_embed
    int wsel = (p == 0 || p == 3) ? 0 : (p == 1 || p == 4) ? 1 : 2;
    const float* w = WT + wsel * DMM * DMM + c;    // coalesced over c
    float bias = (wsel == 0) ? b0[c] : (wsel == 1) ? b1[c] : b2[c];

    float acc[R1];
#pragma unroll
    for (int r = 0; r < R1; r++) acc[r] = bias;
#pragma unroll 4
    for (int d = 0; d < DMM; d++) {
        float wv = w[(size_t)d * DMM];             // read W once per block
#pragma unroll
        for (int r = 0; r < R1; r++) acc[r] = fmaf(xs[tsel][r][d], wv, acc[r]);
    }

    int h = c >> 4, dk = c & 15;
#pragma unroll
    for (int r = 0; r < R1; r++) {
        int srow = row0 + r;
        int bb = srow >> 11, ss = srow & 2047;
        size_t base = ((size_t)(bb * HH + h) * SS + ss);
        if (p == 0)      qp[base * 32 + dk]      = acc[r] * 0.25f;  // scale on q half
        else if (p == 1) kp[base * 32 + dk]      = acc[r];
        else if (p == 2) vp[base * 16 + dk]      = acc[r];
        else if (p == 3) qp[base * 32 + 16 + dk] = acc[r];
        else             kp[base * 32 + 16 + dk] = acc[r];
    }
}

// Flash attention: block = 4 waves. Lanes = 64 q-rows; wave g handles keys
// [kt*64 + g*16, +16) per tile. q' in regs; k'/v wave-uniform global loads.
__global__ __launch_bounds__(256, 4) void k_attn(
    const float* __restrict__ qp, const float* __restrict__ kp,
    const float* __restrict__ vp, float* __restrict__ xout)
{
    __shared__ float rm[256];
    __shared__ float rl[256];
    __shared__ float ro[256][17];   // +1 pad
    int tid = threadIdx.x;
    int r = tid & 63, g = tid >> 6;
    int q0 = blockIdx.x * 64;
    int bh = blockIdx.y;
    const float* qpb = qp + (size_t)bh * SS * 32;
    const float* kpb = kp + (size_t)bh * SS * 32;
    const float* vpb = vp + (size_t)bh * SS * 16;

    float4 qv[8];
    const float4* qptr = (const float4*)(qpb + (size_t)(q0 + r) * 32);
#pragma unroll
    for (int i = 0; i < 8; i++) qv[i] = qptr[i];

    float m = -INFINITY, l = 0.f;
    float o[16];
#pragma unroll
    for (int d = 0; d < 16; d++) o[d] = 0.f;

    for (int kt = 0; kt < 32; kt++) {
        int kbase = kt * 64 + g * 16;
        float sc[16];
        float tmax = m;
#pragma unroll
        for (int j = 0; j < 16; j++) {
            const float4* kr = (const float4*)(kpb + (size_t)(kbase + j) * 32);
            float s = 0.f;
#pragma unroll
            for (int i = 0; i < 8; i++) {
                float4 kv = kr[i];
                s = fmaf(qv[i].x, kv.x, s);
                s = fmaf(qv[i].y, kv.y, s);
                s = fmaf(qv[i].z, kv.z, s);
                s = fmaf(qv[i].w, kv.w, s);
            }
            sc[j] = s;
            tmax = fmaxf(tmax, s);
        }
        float alpha = __expf(m - tmax);   // first tile: exp(-inf)=0
        l *= alpha;
#pragma unroll
        for (int d = 0; d < 16; d++) o[d] *= alpha;
#pragma unroll
        for (int j = 0; j < 16; j++) {
            float pj = __expf(sc[j] - tmax);
            l += pj;
            const float4* vr = (const float4*)(vpb + (size_t)(kbase + j) * 16);
            float4 va = vr[0], vb = vr[1], vc = vr[2], vd = vr[3];
            o[0]  = fmaf(pj, va.x, o[0]);  o[1]  = fmaf(pj, va.y, o[1]);
            o[2]  = fmaf(pj, va.z, o[2]);  o[3]  = fmaf(pj, va.w, o[3]);
            o[4]  = fmaf(pj, vb.x, o[4]);  o[5]  = fmaf(pj, vb.y, o[5]);
            o[6]  = fmaf(pj, vb.z, o[6]);  o[7]  = fmaf(pj, vb.w, o[7]);
            o[8]  = fmaf(pj, vc.x, o[8]);  o[9]  = fmaf(pj, vc.y, o[9]);
            o[10] = fmaf(pj, vc.z, o[10]); o[11] = fmaf(pj, vc.w, o[11]);
            o[12] = fmaf(pj, vd.x, o[12]); o[13] = fmaf(pj, vd.y, o[13]);
            o[14] = fmaf(pj, vd.z, o[14]); o[15] = fmaf(pj, vd.w, o[15]);
        }
        m = tmax;
    }

    rm[tid] = m; rl[tid] = l;
#pragma unroll
    for (int d = 0; d < 16; d++) ro[tid][d] = o[d];
    __syncthreads();

    if (tid < 64) {
        int rr = tid;
        float m0 = rm[rr], m1 = rm[rr + 64], m2 = rm[rr + 128], m3 = rm[rr + 192];
        float M = fmaxf(fmaxf(m0, m1), fmaxf(m2, m3));
        float w0 = __expf(m0 - M), w1 = __expf(m1 - M);
        float w2 = __expf(m2 - M), w3 = __expf(m3 - M);
        float L = rl[rr] * w0 + rl[rr + 64] * w1 + rl[rr + 128] * w2 + rl[rr + 192] * w3;
        float inv = 1.0f / L;
        int b = bh >> 3, h = bh & 7;
        float* op = xout + ((size_t)b * SS + q0 + rr) * DMM + h * DKK;
#pragma unroll
        for (int d = 0; d < 16; d++) {
            op[d] = (ro[rr][d] * w0 + ro[rr + 64][d] * w1 +
                     ro[rr + 128][d] * w2 + ro[rr + 192][d] * w3) * inv;
        }
    }
}

#define R3 16
__global__ __launch_bounds__(128) void k_out(
    const float* __restrict__ x, const float* __restrict__ WoT,
    const float* __restrict__ bo, float* __restrict__ out)
{
    __shared__ float xs[R3][DMM];
    int tid = threadIdx.x;
    int row0 = blockIdx.x * R3;
    for (int idx = tid; idx < R3 * 32; idx += 128) {
        int r = idx >> 5, c4 = idx & 31;
        ((float4*)&xs[r][0])[c4] = ((const float4*)(x + (size_t)(row0 + r) * DMM))[c4];
    }
    __syncthreads();
    float acc[R3];
    float bias = bo[tid];
#pragma unroll
    for (int r = 0; r < R3; r++) acc[r] = bias;
#pragma unroll 4
    for (int d = 0; d < DMM; d++) {
        float wv = WoT[(size_t)d * DMM + tid];
#pragma unroll
        for (int r = 0; r < R3; r++) acc[r] = fmaf(xs[r][d], wv, acc[r]);
    }
    for (int r = 0; r < R3; r++) out[(size_t)(row0 + r) * DMM + tid] = acc[r];
}

extern "C" void kernel_launch(void* const* d_in, const int* in_sizes, int n_in,
                              void* d_out, int out_size, void* d_ws, size_t ws_size,
                              hipStream_t stream)
{
    const float* query = (const float*)d_in[0];
    const float* key   = (const float*)d_in[1];
    const float* value = (const float*)d_in[2];
    const float* pos   = (const float*)d_in[3];
    const float* W0 = (const float*)d_in[4];
    const float* b0 = (const float*)d_in[5];
    const float* W1 = (const float*)d_in[6];
    const float* b1 = (const float*)d_in[7];
    const float* W2 = (const float*)d_in[8];
    const float* b2 = (const float*)d_in[9];
    const float* Wo = (const float*)d_in[10];
    const float* bo = (const float*)d_in[11];
    float* ws = (float*)d_ws;
    float* qp = ws + O_QP;
    float* kp = ws + O_KP;
    float* vp = ws + O_VP;
    float* x  = ws + O_X;
    float* wt = ws + O_WT;
    float* out = (float*)d_out;

    k_transpose<<<dim3(64, 4), 256, 0, stream>>>(W0, W1, W2, Wo, wt);
    k_proj<<<dim3(512), 640, 0, stream>>>(query, key, value, pos, wt, b0, b1, b2,
                                          qp, kp, vp);
    k_attn<<<dim3(32, 32), 256, 0, stream>>>(qp, kp, vp, x);
    k_out<<<dim3(512), 128, 0, stream>>>(x, wt + 3 * DMM * DMM, bo, out);
}

// Round 2
// 187.895 us; speedup vs baseline: 5.3479x; 5.3479x over previous
//
#include <hip/hip_runtime.h>
#include <math.h>

#define LOG2E 1.44269504088896340736f

typedef __attribute__((ext_vector_type(8))) short bfrag;   // 8 x bf16
typedef __attribute__((ext_vector_type(4))) float f4;

// ---------- helpers ----------
__device__ __forceinline__ unsigned pk_trunc(float a, float b) {
    return (__float_as_uint(a) >> 16) | (__float_as_uint(b) & 0xFFFF0000u);
}
__device__ __forceinline__ unsigned pk_rne(float a, float b) {
    unsigned ua = __float_as_uint(a); ua += 0x7FFFu + ((ua >> 16) & 1u);
    unsigned ub = __float_as_uint(b); ub += 0x7FFFu + ((ub >> 16) & 1u);
    return (ua >> 16) | (ub & 0xFFFF0000u);
}
__device__ __forceinline__ float fexp2(float x) {
#if __has_builtin(__builtin_amdgcn_exp2f)
    return __builtin_amdgcn_exp2f(x);
#else
    return exp2f(x);
#endif
}
// async global->LDS, 16B/lane. lds_base must be wave-uniform; HW lands lane i at base+i*16.
__device__ __forceinline__ void stage16(void* lds_base, const void* g) {
#if __has_builtin(__builtin_amdgcn_global_load_lds)
    __builtin_amdgcn_global_load_lds(
        (const __attribute__((address_space(1))) unsigned int*)g,
        (__attribute__((address_space(3))) unsigned int*)lds_base, 16, 0, 0);
#else
    int lane = threadIdx.x & 63;
    *(float4*)((char*)lds_base + lane * 16) = *(const float4*)g;
#endif
}

// workspace byte offsets
#define WS_QHI 0u
#define WS_QLO 4194304u
#define WS_KHI 8388608u
#define WS_KLO 12582912u
#define WS_VT  16777216u
#define WS_X   18874368u
#define WS_WT  23068672u

// ---------- weight transpose ----------
__global__ __launch_bounds__(256) void k_transpose(
    const float* __restrict__ W0, const float* __restrict__ W1,
    const float* __restrict__ W2, const float* __restrict__ Wo,
    float* __restrict__ WT)
{
    int i = blockIdx.x * 256 + threadIdx.x;      // 0..16383
    const float* src = (blockIdx.y == 0) ? W0 : (blockIdx.y == 1) ? W1
                     : (blockIdx.y == 2) ? W2 : Wo;
    float* dst = WT + blockIdx.y * (128 * 128);
    dst[(i & 127) * 128 + (i >> 7)] = src[i];    // WT[d][c] = W[c][d]
}

// ---------- fused projections ----------
// p=0 q(W0)->q' low half (scaled 0.25*log2e), 1 k(W1)->k' low, 2 v(W2)->vT,
// 3 pos_q(W0)->q' high half (scaled log2e), 4 pos_k(W1)->k' high
#define R1 16
__global__ __launch_bounds__(640) void k_proj(
    const float* __restrict__ q_in, const float* __restrict__ k_in,
    const float* __restrict__ v_in, const float* __restrict__ p_in,
    const float* __restrict__ WT,
    const float* __restrict__ b0, const float* __restrict__ b1,
    const float* __restrict__ b2,
    unsigned short* __restrict__ qhi, unsigned short* __restrict__ qlo,
    unsigned short* __restrict__ khi, unsigned short* __restrict__ klo,
    unsigned* __restrict__ vt)
{
    __shared__ float xs[4][R1][128];   // 32 KB
    int tid = threadIdx.x;
    int row0 = blockIdx.x * R1;
    for (int idx = tid; idx < 4 * R1 * 32; idx += 640) {
        int t = idx >> 9, rem = idx & 511;
        int r = rem >> 5, c4 = rem & 31;
        const float* sp = (t == 0) ? q_in : (t == 1) ? k_in : (t == 2) ? v_in : p_in;
        ((float4*)&xs[t][r][0])[c4] = ((const float4*)(sp + (size_t)(row0 + r) * 128))[c4];
    }
    __syncthreads();

    int p = tid >> 7, c = tid & 127;               // wave-uniform p
    int tsel = (p < 3) ? p : 3;
    int wsel = (p == 0 || p == 3) ? 0 : (p == 1 || p == 4) ? 1 : 2;
    const float* w = WT + wsel * 128 * 128 + c;
    float bias = (wsel == 0) ? b0[c] : (wsel == 1) ? b1[c] : b2[c];

    float acc[R1];
#pragma unroll
    for (int r = 0; r < R1; r++) acc[r] = bias;
#pragma unroll 4
    for (int d = 0; d < 128; d++) {
        float wv = w[(size_t)d * 128];
#pragma unroll
        for (int r = 0; r < R1; r++) acc[r] = fmaf(xs[tsel][r][d], wv, acc[r]);
    }

    int h = c >> 4, dk = c & 15;
    int bb = row0 >> 11, ss0 = row0 & 2047;
    if (p == 2) {
        unsigned* vtp = vt + ((((size_t)(bb * 8 + h)) * 16 + dk) * 2048 + ss0) / 2;
#pragma unroll
        for (int r = 0; r < R1; r += 2)
            vtp[r >> 1] = pk_rne(acc[r], acc[r + 1]);
    } else {
        float scale = (p == 0) ? 0.25f * LOG2E : (p == 3) ? LOG2E : 1.0f;
        int off = (p <= 1) ? dk : 16 + dk;
        unsigned short* hp = (p == 0 || p == 3) ? qhi : khi;
        unsigned short* lp = (p == 0 || p == 3) ? qlo : klo;
        size_t rowbase = ((size_t)(bb * 8 + h)) * 2048 + ss0;
#pragma unroll
        for (int r = 0; r < R1; r++) {
            float v = acc[r] * scale;
            unsigned uv = __float_as_uint(v);
            float hif = __uint_as_float(uv & 0xFFFF0000u);
            size_t idx = (rowbase + r) * 32 + off;
            hp[idx] = (unsigned short)(uv >> 16);
            lp[idx] = (unsigned short)(__float_as_uint(v - hif) >> 16);
        }
    }
}

// ---------- fused flash attention (MFMA) ----------
// Block = 4 waves; wave w owns q-rows [blockIdx.x*64 + w*16, +16), all keys.
// Per 32-key chunk: stage k'hi/k'lo [32keys][32dims] + vT [16dims][32keys] bf16
// into double-buffered LDS; S = 3 MFMAs/subtile (hi/lo split), exp2, P->LDS
// roundtrip (C-layout -> A-layout), PV 1 MFMA. No online max (scores bounded).
__global__ __launch_bounds__(256) void k_attn(
    const unsigned short* __restrict__ qhi, const unsigned short* __restrict__ qlo,
    const unsigned short* __restrict__ khi, const unsigned short* __restrict__ klo,
    const unsigned short* __restrict__ vt, float* __restrict__ xout)
{
    __shared__ __align__(16) char kbuf[2][5120];   // [khi 2K | klo 2K | vT 1K] x2
    __shared__ __align__(16) float pS[4][16][36];  // per-wave P scratch (+4 pad)

    const int tid = threadIdx.x;
    const int w = tid >> 6, lane = tid & 63;
    const int qd = lane >> 4, c = lane & 15;
    const int bh = blockIdx.y;
    const int q0 = blockIdx.x * 64 + w * 16;

    const char* khi_bh = (const char*)khi + (size_t)bh * 2048 * 64;
    const char* klo_bh = (const char*)klo + (size_t)bh * 2048 * 64;
    const char* vt_bh  = (const char*)vt  + (size_t)bh * 16 * 4096;

    // persistent A-fragments: q' rows q0+c, dims qd*8..+7 (A[m=lane&15][k=quad*8+j])
    size_t qoff = ((size_t)bh * 2048 + q0 + c) * 64 + qd * 16;
    bfrag qhf = *(const bfrag*)((const char*)qhi + qoff);
    bfrag qlf = *(const bfrag*)((const char*)qlo + qoff);

    auto stage = [&](int boff, int kc) {
        char* db = &kbuf[0][0] + boff;
        const char* s1 = ((w < 2) ? khi_bh : klo_bh) + kc * 2048 + (w & 1) * 1024 + lane * 16;
        stage16(db + w * 1024, s1);
        if (w == 0) {   // wave-uniform branch: wave 0 also stages the vT slice
            const char* vs = vt_bh + (lane >> 2) * 4096 + kc * 64 + (lane & 3) * 16;
            stage16(db + 4096, vs);
        }
    };

    f4 o = {0.f, 0.f, 0.f, 0.f};
    float lsum[4] = {0.f, 0.f, 0.f, 0.f};
    const int koff = c * 64 + qd * 16;
    float* pw = &pS[w][qd * 4][c];
    const float* pr = &pS[w][c][qd * 8];

    stage(0, 0);
    int boff = 0;
    for (int ch = 0; ch < 64; ++ch) {
        __syncthreads();                      // drains staged chunk ch (vmcnt0+barrier)
        if (ch < 63) stage(boff ^ 5120, ch + 1);

        const char* kb = &kbuf[0][0] + boff;
        bfrag kh0 = *(const bfrag*)(kb + koff);           // B[k=qd*8+j][n=key c]
        bfrag kh1 = *(const bfrag*)(kb + koff + 1024);    // keys 16+c
        bfrag kl0 = *(const bfrag*)(kb + koff + 2048);
        bfrag kl1 = *(const bfrag*)(kb + koff + 3072);
        bfrag vf  = *(const bfrag*)(kb + koff + 4096);    // B[k=key qd*8+j][n=dim c]

        f4 s0 = {0.f, 0.f, 0.f, 0.f}, s1 = {0.f, 0.f, 0.f, 0.f};
        s0 = __builtin_amdgcn_mfma_f32_16x16x32_bf16(qhf, kh0, s0, 0, 0, 0);
        s0 = __builtin_amdgcn_mfma_f32_16x16x32_bf16(qhf, kl0, s0, 0, 0, 0);
        s0 = __builtin_amdgcn_mfma_f32_16x16x32_bf16(qlf, kh0, s0, 0, 0, 0);
        s1 = __builtin_amdgcn_mfma_f32_16x16x32_bf16(qhf, kh1, s1, 0, 0, 0);
        s1 = __builtin_amdgcn_mfma_f32_16x16x32_bf16(qhf, kl1, s1, 0, 0, 0);
        s1 = __builtin_amdgcn_mfma_f32_16x16x32_bf16(qlf, kh1, s1, 0, 0, 0);

        float p0[4], p1[4];
#pragma unroll
        for (int r = 0; r < 4; ++r) {
            p0[r] = fexp2(s0[r]);             // C row = qd*4+r, col = key c / 16+c
            p1[r] = fexp2(s1[r]);
            lsum[r] += p0[r] + p1[r];
            pw[r * 36] = p0[r];
            pw[r * 36 + 16] = p1[r];
        }
        // P: C-layout -> A-layout via per-wave LDS (same-wave ds order is safe)
        float4 pa = *(const float4*)pr;
        float4 pb = *(const float4*)(pr + 4);
        union { unsigned u[4]; bfrag v; } pu;
        pu.u[0] = pk_trunc(pa.x, pa.y);
        pu.u[1] = pk_trunc(pa.z, pa.w);
        pu.u[2] = pk_trunc(pb.x, pb.y);
        pu.u[3] = pk_trunc(pb.z, pb.w);
        o = __builtin_amdgcn_mfma_f32_16x16x32_bf16(pu.v, vf, o, 0, 0, 0);
        boff ^= 5120;
    }

    // row sums: reduce over 16 lanes within quad (cols)
#pragma unroll
    for (int m = 1; m <= 8; m <<= 1) {
#pragma unroll
        for (int r = 0; r < 4; ++r) lsum[r] += __shfl_xor(lsum[r], m, 64);
    }
    const int bb = bh >> 3, h = bh & 7;
#pragma unroll
    for (int r = 0; r < 4; ++r) {
        float inv = 1.0f / lsum[r];
        xout[((size_t)(bb * 2048 + q0 + qd * 4 + r)) * 128 + h * 16 + c] = o[r] * inv;
    }
}

// ---------- output projection ----------
#define R3 16
__global__ __launch_bounds__(128) void k_out(
    const float* __restrict__ x, const float* __restrict__ WoT,
    const float* __restrict__ bo, float* __restrict__ out)
{
    __shared__ float xs[R3][128];
    int tid = threadIdx.x;
    int row0 = blockIdx.x * R3;
    for (int idx = tid; idx < R3 * 32; idx += 128) {
        int r = idx >> 5, c4 = idx & 31;
        ((float4*)&xs[r][0])[c4] = ((const float4*)(x + (size_t)(row0 + r) * 128))[c4];
    }
    __syncthreads();
    float acc[R3];
    float bias = bo[tid];
#pragma unroll
    for (int r = 0; r < R3; r++) acc[r] = bias;
#pragma unroll 4
    for (int d = 0; d < 128; d++) {
        float wv = WoT[(size_t)d * 128 + tid];
#pragma unroll
        for (int r = 0; r < R3; r++) acc[r] = fmaf(xs[r][d], wv, acc[r]);
    }
    for (int r = 0; r < R3; r++) out[(size_t)(row0 + r) * 128 + tid] = acc[r];
}

extern "C" void kernel_launch(void* const* d_in, const int* in_sizes, int n_in,
                              void* d_out, int out_size, void* d_ws, size_t ws_size,
                              hipStream_t stream)
{
    const float* query = (const float*)d_in[0];
    const float* key   = (const float*)d_in[1];
    const float* value = (const float*)d_in[2];
    const float* pos   = (const float*)d_in[3];
    const float* W0 = (const float*)d_in[4];
    const float* b0 = (const float*)d_in[5];
    const float* W1 = (const float*)d_in[6];
    const float* b1 = (const float*)d_in[7];
    const float* W2 = (const float*)d_in[8];
    const float* b2 = (const float*)d_in[9];
    const float* Wo = (const float*)d_in[10];
    const float* bo = (const float*)d_in[11];

    char* ws = (char*)d_ws;
    unsigned short* qhi = (unsigned short*)(ws + WS_QHI);
    unsigned short* qlo = (unsigned short*)(ws + WS_QLO);
    unsigned short* khi = (unsigned short*)(ws + WS_KHI);
    unsigned short* klo = (unsigned short*)(ws + WS_KLO);
    unsigned short* vt  = (unsigned short*)(ws + WS_VT);
    float* x  = (float*)(ws + WS_X);
    float* wt = (float*)(ws + WS_WT);
    float* out = (float*)d_out;

    k_transpose<<<dim3(64, 4), 256, 0, stream>>>(W0, W1, W2, Wo, wt);
    k_proj<<<dim3(512), 640, 0, stream>>>(query, key, value, pos, wt, b0, b1, b2,
                                          qhi, qlo, khi, klo, (unsigned*)vt);
    k_attn<<<dim3(32, 32), 256, 0, stream>>>(qhi, qlo, khi, klo, vt, x);
    k_out<<<dim3(512), 128, 0, stream>>>(x, wt + 3 * 128 * 128, bo, out);
}